// Round 3
// baseline (670.852 us; speedup 1.0000x reference)
//
#include <hip/hip_runtime.h>
#include <hip/hip_bf16.h>

// BinaryLinear: out = x @ sign(W)^T
// x: [32,4096,1024] f32 -> A [M=131072][K=1024]
// W: [1024,1024] f32    -> B^T = sign(W) [N=1024][K=1024] bf16 in d_ws (once)
// out: [M][N] f32
//
// R3 changes vs R2 (557us, MfmaUtil 21%, VALUBusy 38%, not mem-bound):
//  T14 async-STAGE split: per iteration, (1) ISSUE B-gll + A-f32 loads for kk+1,
//  (2) ds_read + 32 MFMA on kk (A-load latency hides under MFMA),
//  (3) vmcnt-wait lands here -> cvt_pk + ds_write into next buffer, (4) barrier.
//  K-loop manually unrolled x2 so buffer index is static. Sync structure
//  (1 barrier/iter, dbuf) unchanged from verified R1/R2.

typedef __attribute__((ext_vector_type(8))) short bf16x8;
typedef __attribute__((ext_vector_type(4))) float f32x4;

#define BM 128
#define BN 256
#define BK 32
#define KDIM 1024
#define NDIM 1024
#define NKSTEP (KDIM / BK)
#define PADA 40  // ushorts per sA row: 32 data + 8 pad => 80-byte rows

__device__ __forceinline__ unsigned cvt2(float a, float b) {
  unsigned r;
  asm("v_cvt_pk_bf16_f32 %0, %1, %2" : "=v"(r) : "v"(a), "v"(b));
  return r;
}

// ---- pre-kernel: Bs[n][k] = sign(W[n][k]) as bf16 (+1, -1, or 0) ----
__global__ void sign_kernel(const float4* __restrict__ W, ushort4* __restrict__ Bs, int n4) {
  int i = blockIdx.x * blockDim.x + threadIdx.x;
  if (i >= n4) return;
  float4 v = W[i];
  const float* pv = (const float*)&v;
  ushort4 r;
  unsigned short* pr = (unsigned short*)&r;
#pragma unroll
  for (int j = 0; j < 4; ++j) {
    union { float f; unsigned int u; } c; c.f = pv[j];
    pr[j] = ((c.u & 0x7fffffffu) == 0u)
                ? (unsigned short)0
                : (unsigned short)(0x3f80u | ((c.u >> 16) & 0x8000u));
  }
  Bs[i] = r;
}

// ---- main GEMM ----
__global__ __launch_bounds__(256) void bgemm_kernel(
    const float* __restrict__ X,
    const unsigned short* __restrict__ Bs,
    float* __restrict__ O) {
  __shared__ unsigned short sA[2][BM * PADA];  // 2 x 10240 B
  __shared__ unsigned short sB[2][BN * BK];    // 2 x 16384 B  (53.25 KB -> 3 blocks/CU)

  const int t = threadIdx.x;
  const int l = t & 63;
  const int w = t >> 6;
  const int wr = w >> 1;
  const int wc = w & 1;

  // XCD-bijective swizzle: 4 N-tiles of one M-tile adjacent on the SAME XCD.
  const unsigned nwg = gridDim.x;
  unsigned swz = blockIdx.x;
  if ((nwg & 7u) == 0u) swz = (blockIdx.x & 7u) * (nwg >> 3) + (blockIdx.x >> 3);
  const int bm = (int)(swz >> 2);
  const int bn = (int)(swz & 3u);
  const size_t m0 = (size_t)bm * BM;
  const int N0 = bn * BN;

  // A staging: thread t owns row r = t>>1, k-half h = (t&1)*16 (16 contiguous floats)
  const int ar = t >> 1;
  const int ah = (t & 1) * 16;
  const float* ag = X + (m0 + (size_t)ar) * KDIM + ah;
  const int aw = ar * PADA + ah;

  // B staging: 256x32 bf16 = 1024 16B-chunks, 4 per thread, chunk-XOR swizzle
  // pre-applied on the global source; LDS dest linear (gll rule).
  const unsigned short* bg[4];
  int bw[4];
#pragma unroll
  for (int i = 0; i < 4; ++i) {
    int c = i * 256 + t;
    int n = c >> 2;
    int q = c & 3;
    int kb2 = q ^ ((n >> 1) & 3);
    bg[i] = Bs + (size_t)(N0 + n) * KDIM + kb2 * 8;
    bw[i] = c * 8;
  }

  // fragment read offsets
  const int ll = l & 15;
  const int kb = l >> 4;
  int offA[4], offB[8];
#pragma unroll
  for (int i = 0; i < 4; ++i)
    offA[i] = (wr * 64 + i * 16 + ll) * PADA + kb * 8;
#pragma unroll
  for (int j = 0; j < 8; ++j) {
    int n = wc * 128 + j * 16 + ll;
    int q = kb ^ ((n >> 1) & 3);
    offB[j] = n * BK + q * 8;
  }

  f32x4 acc[4][8];
#pragma unroll
  for (int i = 0; i < 4; ++i)
#pragma unroll
    for (int j = 0; j < 8; ++j) acc[i][j] = (f32x4)0.0f;

  // prologue: full stage of tile 0 into buf 0
  {
    const int k0 = 0;
#pragma unroll
    for (int i = 0; i < 4; ++i)
      __builtin_amdgcn_global_load_lds(
          (const __attribute__((address_space(1))) void*)(bg[i] + k0),
          (__attribute__((address_space(3))) void*)(&sB[0][bw[i]]), 16, 0, 0);
    const float4* ap = reinterpret_cast<const float4*>(ag + k0);
    float4 v0 = ap[0], v1 = ap[1], v2 = ap[2], v3 = ap[3];
    uint4 lo, hi;
    lo.x = cvt2(v0.x, v0.y); lo.y = cvt2(v0.z, v0.w);
    lo.z = cvt2(v1.x, v1.y); lo.w = cvt2(v1.z, v1.w);
    hi.x = cvt2(v2.x, v2.y); hi.y = cvt2(v2.z, v2.w);
    hi.z = cvt2(v3.x, v3.y); hi.w = cvt2(v3.z, v3.w);
    *reinterpret_cast<uint4*>(&sA[0][aw]) = lo;
    *reinterpret_cast<uint4*>(&sA[0][aw + 8]) = hi;
  }
  __syncthreads();

  // T14 step: issue loads for kk+1 EARLY; MFMA on kk; convert+write LATE; 1 barrier.
#define STEP(CUR)                                                              \
  {                                                                            \
    const bool pf = (kk + 1 < NKSTEP);                                         \
    float4 v0, v1, v2, v3;                                                     \
    if (pf) {                                                                  \
      const int k0 = (kk + 1) * BK;                                            \
      _Pragma("unroll") for (int i = 0; i < 4; ++i)                            \
          __builtin_amdgcn_global_load_lds(                                    \
              (const __attribute__((address_space(1))) void*)(bg[i] + k0),     \
              (__attribute__((address_space(3))) void*)(&sB[(CUR) ^ 1][bw[i]]),\
              16, 0, 0);                                                       \
      const float4* ap = reinterpret_cast<const float4*>(ag + k0);             \
      v0 = ap[0]; v1 = ap[1]; v2 = ap[2]; v3 = ap[3];                          \
    }                                                                          \
    const unsigned short* sa = sA[CUR];                                        \
    const unsigned short* sb = sB[CUR];                                        \
    bf16x8 av[4];                                                              \
    bf16x8 bv[8];                                                              \
    _Pragma("unroll") for (int i = 0; i < 4; ++i)                              \
        av[i] = *reinterpret_cast<const bf16x8*>(sa + offA[i]);                \
    _Pragma("unroll") for (int j = 0; j < 8; ++j)                              \
        bv[j] = *reinterpret_cast<const bf16x8*>(sb + offB[j]);                \
    _Pragma("unroll") for (int i = 0; i < 4; ++i)                              \
        _Pragma("unroll") for (int j = 0; j < 8; ++j)                          \
            acc[i][j] = __builtin_amdgcn_mfma_f32_16x16x32_bf16(               \
                av[i], bv[j], acc[i][j], 0, 0, 0);                             \
    if (pf) {                                                                  \
      uint4 lo, hi;                                                            \
      lo.x = cvt2(v0.x, v0.y); lo.y = cvt2(v0.z, v0.w);                        \
      lo.z = cvt2(v1.x, v1.y); lo.w = cvt2(v1.z, v1.w);                        \
      hi.x = cvt2(v2.x, v2.y); hi.y = cvt2(v2.z, v2.w);                        \
      hi.z = cvt2(v3.x, v3.y); hi.w = cvt2(v3.z, v3.w);                        \
      *reinterpret_cast<uint4*>(&sA[(CUR) ^ 1][aw]) = lo;                      \
      *reinterpret_cast<uint4*>(&sA[(CUR) ^ 1][aw + 8]) = hi;                  \
    }                                                                          \
    __syncthreads();                                                           \
    ++kk;                                                                      \
  }

  int kk = 0;
  while (kk < NKSTEP) {
    STEP(0)
    STEP(1)
  }
#undef STEP

  // epilogue: C/D layout col = lane&15, row = (lane>>4)*4 + reg
  const int crow = (l >> 4) * 4;
#pragma unroll
  for (int i = 0; i < 4; ++i) {
    const size_t r0 = m0 + wr * 64 + i * 16 + crow;
#pragma unroll
    for (int j = 0; j < 8; ++j) {
      const int col = N0 + wc * 128 + j * 16 + ll;
      float* op = O + r0 * NDIM + col;
#pragma unroll
      for (int e = 0; e < 4; ++e) op[(size_t)e * NDIM] = acc[i][j][e];
    }
  }
}

// ---- fallback (only if ws too small for the 2 MiB sign buffer) ----
__global__ void naive_kernel(const float* __restrict__ X, const float* __restrict__ W,
                             float* __restrict__ O, long long total) {
  long long idx = (long long)blockIdx.x * blockDim.x + threadIdx.x;
  if (idx >= total) return;
  int n = (int)(idx & (NDIM - 1));
  long long m = idx >> 10;
  const float* xr = X + m * KDIM;
  const float* wr = W + (long long)n * KDIM;
  float s = 0.f;
  for (int k = 0; k < KDIM; ++k) {
    float wv = wr[k];
    float sg = (wv > 0.f) ? 1.f : ((wv < 0.f) ? -1.f : 0.f);
    s += xr[k] * sg;
  }
  O[idx] = s;
}

extern "C" void kernel_launch(void* const* d_in, const int* in_sizes, int n_in,
                              void* d_out, int out_size, void* d_ws, size_t ws_size,
                              hipStream_t stream) {
  const float* X = (const float*)d_in[0];
  const float* W = (const float*)d_in[1];
  float* O = (float*)d_out;
  const long long M = (long long)in_sizes[0] / KDIM;  // 131072

  const size_t need_ws = (size_t)NDIM * KDIM * sizeof(unsigned short);  // 2 MiB
  if (ws_size >= need_ws && (M % BM) == 0) {
    unsigned short* Bs = (unsigned short*)d_ws;
    int n4 = (NDIM * KDIM) / 4;
    sign_kernel<<<dim3(n4 / 256), dim3(256), 0, stream>>>(
        (const float4*)W, (ushort4*)Bs, n4);
    dim3 grid((unsigned)((M / BM) * (NDIM / BN)));
    bgemm_kernel<<<grid, dim3(256), 0, stream>>>(X, Bs, O);
  } else {
    long long total = M * NDIM;
    long long blocks = (total + 255) / 256;
    naive_kernel<<<dim3((unsigned)blocks), dim3(256), 0, stream>>>(X, W, O, total);
  }
}